// Round 3
// baseline (120.172 us; speedup 1.0000x reference)
//
#include <hip/hip_runtime.h>
#include <hip/hip_bf16.h>
#include <stdint.h>

// Problem constants
#define BB   32
#define CIN  128
#define HH   64
#define WW   64
#define COUT 256
#define OHH  62
#define OWW  62
#define PIX_PER_B (OHH*OWW)        // 3844
#define NPIX (BB*PIX_PER_B)        // 123008
#define KTOT (9*CIN)               // 1152
#define NKT  18                    // K-tiles of BK=64
#define NTBLK 481                  // ceil(NPIX/256)

typedef __bf16 bf16x8 __attribute__((ext_vector_type(8)));
typedef float  f32x4  __attribute__((ext_vector_type(4)));
typedef uint16_t u16x8 __attribute__((ext_vector_type(8)));

__device__ __forceinline__ uint16_t f2bf(float f) {
    uint32_t u = __float_as_uint(f);
    uint32_t r = (u + 0x7FFFu + ((u >> 16) & 1u)) >> 16;
    return (uint16_t)r;
}

__device__ __forceinline__ void gload_lds16(const void* g, void* l) {
    __builtin_amdgcn_global_load_lds(
        (const __attribute__((address_space(1))) uint32_t*)g,
        (__attribute__((address_space(3))) uint32_t*)l, 16, 0, 0);
}

// -------- Prepass 1: NCHW fp32 -> NHWC bf16 ----------------------------------
__global__ void __launch_bounds__(256) to_nhwc(const float* __restrict__ in,
                                               uint16_t* __restrict__ out) {
    int slab = blockIdx.x;            // b*64 + h
    int b = slab >> 6, h = slab & 63;
    int w  = threadIdx.x & 63;
    int cp = threadIdx.x >> 6;        // 0..3
    const float* src = in + (((size_t)b * CIN) * HH + h) * WW + w;
    uint16_t* dst = out + ((size_t)slab * WW + w) * CIN;
    #pragma unroll
    for (int it = 0; it < 4; ++it) {
        int c0 = cp * 32 + it * 8;
        u16x8 v;
        #pragma unroll
        for (int j = 0; j < 8; ++j) v[j] = f2bf(src[(c0 + j) * (HH * WW)]);
        *reinterpret_cast<u16x8*>(dst + c0) = v;
    }
}

// -------- Prepass 2: OIHW fp32 -> bf16 [o][uv*128 + c] -----------------------
__global__ void __launch_bounds__(256) pack_w(const float* __restrict__ w,
                                              uint16_t* __restrict__ out) {
    int idx = blockIdx.x * 256 + threadIdx.x;     // < 256*1152
    int o = idx / KTOT;
    int k = idx - o * KTOT;
    int uv = k >> 7, c = k & 127;
    out[idx] = f2bf(w[(o * CIN + c) * 9 + uv]);
}

// -------- Main: 256x256 tile, 8 waves (2Mx4N, 128x64 each), BK=64 ------------
// m201-style 8-phase schedule. LDS: [2 buf][2 khalf][A|X][256 rows][32 k] bf16
// = 128 KB. Staging at k-half granularity: 1 half-tile (2 gload_lds of 8KB)
// per phase, into the k-half region freed one phase earlier. vmcnt(4) only at
// phases 4 and 8. Swizzle: stored chunk = c ^ ((row>>1)&3) (16B chunks, 64B
// rows) -> frag ds_read_b128 hits all 32 banks 2x per 16-lane group.
__global__ void __launch_bounds__(512, 2) conv_mfma8(
        const uint16_t* __restrict__ Xg,   // NHWC bf16 [32][64][64][128]
        const uint16_t* __restrict__ Wg,   // bf16 [256][1152], k=(uv,c)
        const float*    __restrict__ bias, // [256]
        float*          __restrict__ out)  // NCHW fp32 [32][256][62][62]
{
    __shared__ char lds[131072 + 2048];
    int* pbase = (int*)(lds + 131072);   // [256] NHWC elem off of pixel
    int* obase = pbase + 256;            // [256] out flat base (o=0), -1=invalid

    const int tid  = threadIdx.x;
    const int lane = tid & 63;
    const int wid  = tid >> 6;           // 0..7

    // bijective XCD swizzle: nwg=481, q=60, r=1
    int bid = blockIdx.x;
    int xcd = bid & 7, lid = bid >> 3;
    int nt  = (xcd == 0 ? lid : 61 + (xcd - 1) * 60 + lid);

    if (tid < 256) {
        int n     = nt * 256 + tid;
        int valid = n < NPIX;
        int nn    = valid ? n : NPIX - 1;
        int b     = nn / PIX_PER_B;
        int rem   = nn - b * PIX_PER_B;
        int oh    = rem / OWW;
        int ow    = rem - oh * OWW;
        pbase[tid] = ((b * 64 + oh) * 64 + ow) * 128;
        obase[tid] = valid ? b * (COUT * PIX_PER_B) + rem : -1;
    }
    __syncthreads();

    // ---- staging geometry (per thread, both loads of a half-tile) ----
    // load l covers row = l*128 + (tid>>2), stored chunk sc = tid&3.
    // logical chunk c = sc ^ ((row>>1)&3) = (tid&3) ^ ((tid>>3)&3)  (same for l=0,1)
    const int cs   = (((tid & 3) ^ ((tid >> 3) & 3)) << 4);  // logical chunk byte off
    const int ldst = tid * 16;
    const char* WgB = (const char*)Wg;
    const char* XgB = (const char*)Xg;
    int aow[2], pxw[2];
    aow[0] = (tid >> 2) * (KTOT * 2);
    aow[1] = (128 + (tid >> 2)) * (KTOT * 2);
    pxw[0] = pbase[tid >> 2] * 2;
    pxw[1] = pbase[128 + (tid >> 2)] * 2;

    auto stage = [&](int t, int kh, int op) {   // op: 0=A(weights), 1=X(pixels)
        if (t >= NKT) return;
        char* region = lds + (t & 1) * 65536 + kh * 32768 + op * 16384;
        int uvv = t >> 1;                       // 0..8
        int u   = (uvv * 11) >> 5;              // uvv / 3
        int v   = uvv - u * 3;
        int kb  = ((t & 1) << 7) + (kh << 6) + cs;
        if (op == 0) {
            int kf = uvv * 256 + kb;
            gload_lds16(WgB + aow[0] + kf, region + ldst);
            gload_lds16(WgB + aow[1] + kf, region + 8192 + ldst);
        } else {
            int kf = (u * 64 + v) * 256 + kb;
            gload_lds16(XgB + pxw[0] + kf, region + ldst);
            gload_lds16(XgB + pxw[1] + kf, region + 8192 + ldst);
        }
    };

    // ---- fragment ds_read byte offsets (within a [256][32] region) ----
    const int wm = wid >> 2, wn = wid & 3;      // 2 M-waves x 4 N-waves
    int aoff_frag[8], xoff_frag[4];
    #pragma unroll
    for (int a = 0; a < 2; ++a)
        #pragma unroll
        for (int mi = 0; mi < 4; ++mi) {
            int row = wm * 128 + a * 64 + mi * 16 + (lane & 15);
            aoff_frag[a * 4 + mi] = row * 64 +
                ((((lane >> 4) ^ ((row >> 1) & 3))) << 4);
        }
    #pragma unroll
    for (int nj = 0; nj < 4; ++nj) {
        int row = wn * 64 + nj * 16 + (lane & 15);
        xoff_frag[nj] = row * 64 + ((((lane >> 4) ^ ((row >> 1) & 3))) << 4);
    }

    f32x4 acc[8][4] = {};
    bf16x8 xf[4];
    char* bA = lds;
    char* bB = lds + 65536;

// Phase: {[reload xf] + read af; stage 1 half-tile; barrier; lgkmcnt(0);
//         setprio(1); 16 MFMA; setprio(0); [vmcnt]; barrier}
#define PHASE(BUFC, A, KS, RX, ST, SKH, SOP, VMC) do {                         \
    char* _kb = (BUFC) + (KS) * 32768;                                         \
    if (RX) { _Pragma("unroll") for (int nj = 0; nj < 4; ++nj)                 \
        xf[nj] = *reinterpret_cast<const bf16x8*>(_kb + 16384 + xoff_frag[nj]); } \
    bf16x8 af[4];                                                              \
    _Pragma("unroll") for (int mi = 0; mi < 4; ++mi)                           \
        af[mi] = *reinterpret_cast<const bf16x8*>(_kb + aoff_frag[(A)*4+mi]);  \
    stage((ST), (SKH), (SOP));                                                 \
    __builtin_amdgcn_s_barrier();                                              \
    asm volatile("s_waitcnt lgkmcnt(0)" ::: "memory");                         \
    __builtin_amdgcn_sched_barrier(0);                                         \
    __builtin_amdgcn_s_setprio(1);                                             \
    _Pragma("unroll") for (int mi = 0; mi < 4; ++mi)                           \
      _Pragma("unroll") for (int nj = 0; nj < 4; ++nj)                         \
        acc[(A)*4+mi][nj] = __builtin_amdgcn_mfma_f32_16x16x32_bf16(           \
            af[mi], xf[nj], acc[(A)*4+mi][nj], 0, 0, 0);                       \
    __builtin_amdgcn_s_setprio(0);                                             \
    if ((VMC) == 1) asm volatile("s_waitcnt vmcnt(4)" ::: "memory");           \
    else if ((VMC) == 2) asm volatile("s_waitcnt vmcnt(0)" ::: "memory");      \
    __builtin_amdgcn_s_barrier();                                              \
    if (VMC) __builtin_amdgcn_sched_barrier(0);                                \
} while (0)

    // ---- prologue: stage tile 0 fully + tile 1 k-half0 (6 halves) ----
    stage(0, 0, 0); stage(0, 0, 1);
    stage(0, 1, 0); stage(0, 1, 1);
    stage(1, 0, 0); stage(1, 0, 1);
    asm volatile("s_waitcnt vmcnt(4)" ::: "memory");   // tile 0 resident
    __builtin_amdgcn_s_barrier();

    // ---- main loop: 9 iters x 2 K-tiles, 8 phases each ----
    for (int i = 0; i < 9; ++i) {
        const int t = 2 * i;
        const int vm = (i == 8) ? 2 : 1;
        PHASE(bA, 0, 0, 1, t + 1, 1, 0, 0);   // ph1: stage A1(t+1) -> B.kh1
        PHASE(bA, 1, 0, 0, t + 1, 1, 1, 0);   // ph2: X1(t+1) -> B.kh1
        PHASE(bA, 0, 1, 1, t + 2, 0, 0, 0);   // ph3: A0(t+2) -> A.kh0
        PHASE(bA, 1, 1, 0, t + 2, 0, 1, vm);  // ph4: X0(t+2); vmcnt
        PHASE(bB, 0, 0, 1, t + 2, 1, 0, 0);   // ph5: A1(t+2) -> A.kh1
        PHASE(bB, 1, 0, 0, t + 2, 1, 1, 0);   // ph6: X1(t+2) -> A.kh1
        PHASE(bB, 0, 1, 1, t + 3, 0, 0, 0);   // ph7: A0(t+3) -> B.kh0
        PHASE(bB, 1, 1, 0, t + 3, 0, 1, vm);  // ph8: X0(t+3); vmcnt
    }
#undef PHASE

    // ---- epilogue: C/D col=lane&15 (pixel), row=(lane>>4)*4+reg (o) ----
    #pragma unroll
    for (int mi = 0; mi < 8; ++mi) {
        int o = wm * 128 + mi * 16 + ((lane >> 4) << 2);
        #pragma unroll
        for (int reg = 0; reg < 4; ++reg) {
            float bv = bias[o + reg];
            #pragma unroll
            for (int nj = 0; nj < 4; ++nj) {
                int pl = wn * 64 + nj * 16 + (lane & 15);
                int ob = obase[pl];
                if (ob >= 0) out[ob + (o + reg) * PIX_PER_B] = acc[mi][nj][reg] + bv;
            }
        }
    }
}

// -------- Fallback (ws too small): naive direct conv -------------------------
__global__ void __launch_bounds__(256) conv_naive(const float* __restrict__ in,
                                                  const float* __restrict__ w,
                                                  const float* __restrict__ bias,
                                                  float* __restrict__ out) {
    long idx = (long)blockIdx.x * 256 + threadIdx.x;
    int t = (int)idx;
    int ow = t % OWW; t /= OWW;
    int oh = t % OHH; t /= OHH;
    int o  = t % COUT;
    int b  = t / COUT;
    float s = bias[o];
    for (int c = 0; c < CIN; ++c)
        for (int u = 0; u < 3; ++u)
            for (int v = 0; v < 3; ++v)
                s += in[((b * CIN + c) * HH + oh + u) * WW + ow + v] *
                     w[((o * CIN + c) * 3 + u) * 3 + v];
    out[idx] = s;
}

extern "C" void kernel_launch(void* const* d_in, const int* in_sizes, int n_in,
                              void* d_out, int out_size, void* d_ws, size_t ws_size,
                              hipStream_t stream) {
    const float* in   = (const float*)d_in[0];
    const float* wt   = (const float*)d_in[1];
    const float* bias = (const float*)d_in[2];
    float* out = (float*)d_out;

    const size_t xg_elems = (size_t)BB * HH * WW * CIN;       // 33.5M bf16
    const size_t wg_elems = (size_t)COUT * KTOT;              // 295K bf16
    const size_t need = (xg_elems + wg_elems) * sizeof(uint16_t);

    if (ws_size < need) {
        long total = (long)BB * COUT * OHH * OWW;
        conv_naive<<<(int)((total + 255) / 256), 256, 0, stream>>>(in, wt, bias, out);
        return;
    }

    uint16_t* Xg = (uint16_t*)d_ws;
    uint16_t* Wg = Xg + xg_elems;

    to_nhwc<<<BB * HH, 256, 0, stream>>>(in, Xg);
    pack_w<<<(COUT * KTOT) / 256, 256, 0, stream>>>(wt, Wg);
    conv_mfma8<<<NTBLK, 512, 0, stream>>>(Xg, Wg, bias, out);
}

// Round 4
// 109.606 us; speedup vs baseline: 1.0964x; 1.0964x over previous
//
#include <hip/hip_runtime.h>
#include <hip/hip_bf16.h>
#include <stdint.h>

// Problem constants
#define BB   32
#define CIN  128
#define HH   64
#define WW   64
#define COUT 256
#define OHH  62
#define OWW  62
#define PIX_PER_B (OHH*OWW)        // 3844
#define NPIX (BB*PIX_PER_B)        // 123008 = 961 * 128
#define KTOT (9*CIN)               // 1152
#define NKT  36                    // K-tiles of BK=32
#define SLOT 24576                 // A 16KB + X 8KB per K-tile

typedef __bf16 bf16x8 __attribute__((ext_vector_type(8)));
typedef float  f32x4  __attribute__((ext_vector_type(4)));
typedef uint16_t u16x8 __attribute__((ext_vector_type(8)));

__device__ __forceinline__ uint16_t f2bf(float f) {
    uint32_t u = __float_as_uint(f);
    uint32_t r = (u + 0x7FFFu + ((u >> 16) & 1u)) >> 16;
    return (uint16_t)r;
}

__device__ __forceinline__ void gload_lds16(const void* g, void* l) {
    __builtin_amdgcn_global_load_lds(
        (const __attribute__((address_space(1))) uint32_t*)g,
        (__attribute__((address_space(3))) uint32_t*)l, 16, 0, 0);
}

// -------- Prepass 1: NCHW fp32 -> NHWC bf16 ----------------------------------
__global__ void __launch_bounds__(256) to_nhwc(const float* __restrict__ in,
                                               uint16_t* __restrict__ out) {
    int slab = blockIdx.x;            // b*64 + h
    int b = slab >> 6, h = slab & 63;
    int w  = threadIdx.x & 63;
    int cp = threadIdx.x >> 6;        // 0..3
    const float* src = in + (((size_t)b * CIN) * HH + h) * WW + w;
    uint16_t* dst = out + ((size_t)slab * WW + w) * CIN;
    #pragma unroll
    for (int it = 0; it < 4; ++it) {
        int c0 = cp * 32 + it * 8;
        u16x8 v;
        #pragma unroll
        for (int j = 0; j < 8; ++j) v[j] = f2bf(src[(c0 + j) * (HH * WW)]);
        *reinterpret_cast<u16x8*>(dst + c0) = v;
    }
}

// -------- Prepass 2: OIHW fp32 -> bf16 [o][uv*128 + c] -----------------------
__global__ void __launch_bounds__(256) pack_w(const float* __restrict__ w,
                                              uint16_t* __restrict__ out) {
    int idx = blockIdx.x * 256 + threadIdx.x;     // < 256*1152
    int o = idx / KTOT;
    int k = idx - o * KTOT;
    int uv = k >> 7, c = k & 127;
    out[idx] = f2bf(w[(o * CIN + c) * 9 + uv]);
}

// -------- Main: 256x128 tile, 8 waves (4Mx2N, 64x64 each), BK=32 -------------
// One phase per K-tile: 8 ds_read_b128 + 3 gload_lds + 16 MFMA per wave.
// Ring-3 LDS slots (24KB each, 73KB total) -> 2 blocks/CU co-resident; 16
// waves/CU from 2 INDEPENDENT blocks hide each other's barriers/staging/
// epilogue. Counted vmcnt(3): stage t+2 during t, drain t+1's loads at end
// of t, never to 0 until the tail. Swizzle: 64B rows, stored chunk =
// c ^ ((row>>1)&3) on both staging source and frag reads (involution).
__global__ void __launch_bounds__(512, 4) conv_k32(
        const uint16_t* __restrict__ Xg,   // NHWC bf16 [32][64][64][128]
        const uint16_t* __restrict__ Wg,   // bf16 [256][1152], k=(uv,c)
        const float*    __restrict__ bias, // [256]
        float*          __restrict__ out)  // NCHW fp32 [32][256][62][62]
{
    __shared__ char lds[3 * SLOT + 1024];
    int* pbase = (int*)(lds + 3 * SLOT);   // [128] NHWC elem off of pixel
    int* obase = pbase + 128;              // [128] out flat base (o=0)

    const int tid  = threadIdx.x;
    const int lane = tid & 63;
    const int wid  = tid >> 6;             // 0..7

    // bijective XCD swizzle: nwg=961, q=120, r=1
    int bid = blockIdx.x;
    int xcd = bid & 7, lid = bid >> 3;
    int nt  = (xcd == 0 ? lid : 121 + (xcd - 1) * 120 + lid);

    if (tid < 128) {
        int n   = nt * 128 + tid;
        int b   = n / PIX_PER_B;
        int rem = n - b * PIX_PER_B;
        int oh  = rem / OWW;
        int ow  = rem - oh * OWW;
        pbase[tid] = ((b * 64 + oh) * 64 + ow) * 128;
        obase[tid] = b * (COUT * PIX_PER_B) + rem;
    }
    __syncthreads();

    // ---- staging geometry ----
    // A load l: row = l*128 + (tid>>2); X: row = tid>>2. stored chunk = tid&3,
    // logical chunk c = (tid&3) ^ ((row>>1)&3) = (tid&3) ^ ((tid>>3)&3).
    const int cs   = (((tid & 3) ^ ((tid >> 3) & 3)) << 4);
    const int ldst = tid * 16;
    const char* WgB = (const char*)Wg;
    const char* XgB = (const char*)Xg;
    const int aow0 = (tid >> 2) * (KTOT * 2);
    const int aow1 = (128 + (tid >> 2)) * (KTOT * 2);
    const int pxw  = pbase[tid >> 2] * 2;

    // ---- fragment ds_read byte offsets ----
    const int wm = wid >> 1, wn = wid & 1;   // 4 M-waves x 2 N-waves
    int aro[4], xro[4];
    #pragma unroll
    for (int mi = 0; mi < 4; ++mi) {
        int row = wm * 64 + mi * 16 + (lane & 15);
        aro[mi] = row * 64 + ((((lane >> 4) ^ ((row >> 1) & 3))) << 4);
    }
    #pragma unroll
    for (int nj = 0; nj < 4; ++nj) {
        int row = wn * 64 + nj * 16 + (lane & 15);
        xro[nj] = 16384 + row * 64 + ((((lane >> 4) ^ ((row >> 1) & 3))) << 4);
    }

    f32x4 acc[4][4] = {};

    auto stage = [&](int t, char* dst) {
        int uvv = t >> 2;                      // 0..8
        int u   = (uvv * 11) >> 5;             // uvv/3
        int v   = uvv - u * 3;
        int kb  = ((t & 3) << 6) + cs;         // k-quarter byte off + chunk
        gload_lds16(WgB + aow0 + uvv * 256 + kb, dst + ldst);
        gload_lds16(WgB + aow1 + uvv * 256 + kb, dst + 8192 + ldst);
        gload_lds16(XgB + pxw + (u * 64 + v) * 256 + kb, dst + 16384 + ldst);
    };

    // ---- prologue: stage K-tiles 0,1 ----
    stage(0, lds);
    stage(1, lds + SLOT);
    asm volatile("s_waitcnt vmcnt(3)" ::: "memory");   // tile 0 resident
    __builtin_amdgcn_s_barrier();

    int s = 0, s2 = 2;
    for (int t = 0; t < NKT; ++t) {
        char* slot = lds + s * SLOT;
        bf16x8 af[4], xf[4];
        #pragma unroll
        for (int mi = 0; mi < 4; ++mi)
            af[mi] = *reinterpret_cast<const bf16x8*>(slot + aro[mi]);
        #pragma unroll
        for (int nj = 0; nj < 4; ++nj)
            xf[nj] = *reinterpret_cast<const bf16x8*>(slot + xro[nj]);
        if (t + 2 < NKT) stage(t + 2, lds + s2 * SLOT);
        __builtin_amdgcn_s_barrier();
        asm volatile("s_waitcnt lgkmcnt(0)" ::: "memory");
        __builtin_amdgcn_sched_barrier(0);
        __builtin_amdgcn_s_setprio(1);
        #pragma unroll
        for (int mi = 0; mi < 4; ++mi)
            #pragma unroll
            for (int nj = 0; nj < 4; ++nj)
                acc[mi][nj] = __builtin_amdgcn_mfma_f32_16x16x32_bf16(
                    af[mi], xf[nj], acc[mi][nj], 0, 0, 0);
        __builtin_amdgcn_s_setprio(0);
        if (t < NKT - 2)
            asm volatile("s_waitcnt vmcnt(3)" ::: "memory");
        else if (t == NKT - 2)
            asm volatile("s_waitcnt vmcnt(0)" ::: "memory");
        __builtin_amdgcn_s_barrier();
        s  = (s  == 2) ? 0 : s  + 1;
        s2 = (s2 == 2) ? 0 : s2 + 1;
    }

    // ---- epilogue: C/D col=lane&15 (pixel), row=(lane>>4)*4+reg (o) ----
    #pragma unroll
    for (int mi = 0; mi < 4; ++mi) {
        int o = wm * 64 + mi * 16 + ((lane >> 4) << 2);
        #pragma unroll
        for (int reg = 0; reg < 4; ++reg) {
            float bv = bias[o + reg];
            #pragma unroll
            for (int nj = 0; nj < 4; ++nj) {
                int pl = wn * 64 + nj * 16 + (lane & 15);
                out[obase[pl] + (o + reg) * PIX_PER_B] = acc[mi][nj][reg] + bv;
            }
        }
    }
}

// -------- Fallback (ws too small): naive direct conv -------------------------
__global__ void __launch_bounds__(256) conv_naive(const float* __restrict__ in,
                                                  const float* __restrict__ w,
                                                  const float* __restrict__ bias,
                                                  float* __restrict__ out) {
    long idx = (long)blockIdx.x * 256 + threadIdx.x;
    int t = (int)idx;
    int ow = t % OWW; t /= OWW;
    int oh = t % OHH; t /= OHH;
    int o  = t % COUT;
    int b  = t / COUT;
    float s = bias[o];
    for (int c = 0; c < CIN; ++c)
        for (int u = 0; u < 3; ++u)
            for (int v = 0; v < 3; ++v)
                s += in[((b * CIN + c) * HH + oh + u) * WW + ow + v] *
                     w[((o * CIN + c) * 3 + u) * 3 + v];
    out[idx] = s;
}

extern "C" void kernel_launch(void* const* d_in, const int* in_sizes, int n_in,
                              void* d_out, int out_size, void* d_ws, size_t ws_size,
                              hipStream_t stream) {
    const float* in   = (const float*)d_in[0];
    const float* wt   = (const float*)d_in[1];
    const float* bias = (const float*)d_in[2];
    float* out = (float*)d_out;

    const size_t xg_elems = (size_t)BB * HH * WW * CIN;       // 33.5M bf16
    const size_t wg_elems = (size_t)COUT * KTOT;              // 295K bf16
    const size_t need = (xg_elems + wg_elems) * sizeof(uint16_t);

    if (ws_size < need) {
        long total = (long)BB * COUT * OHH * OWW;
        conv_naive<<<(int)((total + 255) / 256), 256, 0, stream>>>(in, wt, bias, out);
        return;
    }

    uint16_t* Xg = (uint16_t*)d_ws;
    uint16_t* Wg = Xg + xg_elems;

    to_nhwc<<<BB * HH, 256, 0, stream>>>(in, Xg);
    pack_w<<<(COUT * KTOT) / 256, 256, 0, stream>>>(wt, Wg);
    conv_k32<<<NPIX / 128, 512, 0, stream>>>(Xg, Wg, bias, out);
}